// Round 6
// baseline (277.125 us; speedup 1.0000x reference)
//
#include <hip/hip_runtime.h>
#include <stdint.h>

#define NEG_W 8.0f
#define EPS 1e-7f
#define TPB 256
#define GRID 512                         // 2 blocks/CU (64 KB LDS each)
#define ROUNDS 16
#define F4R (TPB * 4)                    // 1024 float4 per block-round
#define F4B (F4R * ROUNDS)               // 16384 float4 per block; 512*16384 = N/4

typedef const __attribute__((address_space(1))) void* gp_t;
typedef __attribute__((address_space(3))) void* lp_t;

// Hard vmcnt wait; no register operands (the R5 failure mode), "memory"
// clobber orders it against both the LDS-DMA intrinsics and the ds_reads.
#define WAIT8() asm volatile("s_waitcnt vmcnt(8)" ::: "memory")
#define WAIT0() asm volatile("s_waitcnt vmcnt(0)" ::: "memory")
#define CFENCE() asm volatile("" ::: "memory")

__global__ __launch_bounds__(TPB) void bce_partial(
    const float4* __restrict__ out4, const int4* __restrict__ tgt4,
    float* __restrict__ partials) {
  // Double-buffered staging: 2 x (16 KB floats + 16 KB ints) = 64 KB.
  __shared__ float4 sf[2][F4R];
  __shared__ int4 si[2][F4R];

  const int tid = threadIdx.x;
  const long base = (long)blockIdx.x * F4B + tid;
  const float4* po = out4 + base;   // thread's lane-resolved global base
  const int4* pt = tgt4 + base;

  // Issue one round of 8 async 16B direct-to-LDS loads (no dest VGPRs).
  // LDS dest = wave-uniform base + lane*16 by construction (slot j*TPB+tid).
#define ISSUE(r, buf)                                                       \
  do {                                                                      \
    _Pragma("unroll")                                                       \
    for (int j = 0; j < 4; ++j) {                                           \
      __builtin_amdgcn_global_load_lds((gp_t)(po + (r)*F4R + j * TPB),      \
                                       (lp_t)&sf[buf][j * TPB + tid], 16,   \
                                       0, 0);                               \
      __builtin_amdgcn_global_load_lds((gp_t)(pt + (r)*F4R + j * TPB),      \
                                       (lp_t)&si[buf][j * TPB + tid], 16,   \
                                       0, 0);                               \
    }                                                                       \
  } while (0)

  float acc0 = 0.0f, acc1 = 0.0f, acc2 = 0.0f, acc3 = 0.0f;

  ISSUE(0, 0);                        // prologue: round 0 in flight
#pragma unroll
  for (int r = 0; r < ROUNDS; ++r) {
    const int buf = r & 1;
    if (r + 1 < ROUNDS) {
      ISSUE(r + 1, buf ^ 1);          // keep next round's 8 loads flying
      WAIT8();                        // oldest 8 (round r) landed in LDS
    } else {
      WAIT0();
    }
#pragma unroll
    for (int j = 0; j < 4; ++j) {     // consume own slots: 16 elements
      float4 o = sf[buf][j * TPB + tid];
      int4 t = si[buf][j * TPB + tid];
      float x0 = (t.x == 1) ? (o.x + EPS) : (1.0f - o.x + EPS);
      float w0 = (t.x == 1) ? 1.0f : NEG_W;
      float x1 = (t.y == 1) ? (o.y + EPS) : (1.0f - o.y + EPS);
      float w1 = (t.y == 1) ? 1.0f : NEG_W;
      float x2 = (t.z == 1) ? (o.z + EPS) : (1.0f - o.z + EPS);
      float w2 = (t.z == 1) ? 1.0f : NEG_W;
      float x3 = (t.w == 1) ? (o.w + EPS) : (1.0f - o.w + EPS);
      float w3 = (t.w == 1) ? 1.0f : NEG_W;
      acc0 = fmaf(w0, __logf(x0), acc0);
      acc1 = fmaf(w1, __logf(x1), acc1);
      acc2 = fmaf(w2, __logf(x2), acc2);
      acc3 = fmaf(w3, __logf(x3), acc3);
    }
    CFENCE();  // pin ds_reads of buf before next iteration's DMA re-targets it
  }
#undef ISSUE

  float sum = -((acc0 + acc1) + (acc2 + acc3));

  // wave64 butterfly reduce
  for (int off = 32; off > 0; off >>= 1)
    sum += __shfl_down(sum, off, 64);

  __shared__ float wsum[TPB / 64];
  const int lane = threadIdx.x & 63;
  const int wid = threadIdx.x >> 6;
  if (lane == 0) wsum[wid] = sum;
  __syncthreads();
  if (threadIdx.x == 0) {
    float s = 0.0f;
    for (int w = 0; w < TPB / 64; ++w) s += wsum[w];
    partials[blockIdx.x] = s;
  }
}

// Kernel 2: single block reduces GRID float partials in double, writes mean.
__global__ __launch_bounds__(TPB) void bce_finalize(
    const float* __restrict__ partials, float* __restrict__ out, int nblocks,
    double inv_n) {
  double s = 0.0;
  for (int i = threadIdx.x; i < nblocks; i += TPB) s += (double)partials[i];
  for (int off = 32; off > 0; off >>= 1)
    s += __shfl_down(s, off, 64);
  __shared__ double wsum[TPB / 64];
  const int lane = threadIdx.x & 63;
  const int wid = threadIdx.x >> 6;
  if (lane == 0) wsum[wid] = s;
  __syncthreads();
  if (threadIdx.x == 0) {
    double tot = 0.0;
    for (int w = 0; w < TPB / 64; ++w) tot += wsum[w];
    out[0] = (float)(tot * inv_n);
  }
}

extern "C" void kernel_launch(void* const* d_in, const int* in_sizes, int n_in,
                              void* d_out, int out_size, void* d_ws, size_t ws_size,
                              hipStream_t stream) {
  const float4* out4 = (const float4*)d_in[0];
  const int4* tgt4 = (const int4*)d_in[1];
  float* partials = (float*)d_ws;  // GRID * 4 B scratch

  bce_partial<<<GRID, TPB, 0, stream>>>(out4, tgt4, partials);
  bce_finalize<<<1, TPB, 0, stream>>>(partials, (float*)d_out, GRID,
                                      1.0 / (double)33554432);
}